// Round 14
// baseline (151.173 us; speedup 1.0000x reference)
//
#include <hip/hip_runtime.h>
#include <stdint.h>

// Problem constants (match reference)
#define N_Q   50000
#define N_S   100000
#define KNB   32
#define NKP   27
#define CH    64            // IN == OUT == 64
#define KP_EXT 0.057735026918962584f   // 2*0.1/(KP-1)/sqrt(3)
#define BBOX  0.158f                    // 0.1 + KP_EXT + margin
#define NEG_SLOPE 0.01f
#define QSCALE 500.0f                   // quantization: 0.002 resolution
#define QTH    81                       // |du|<=81 conservative (hit => <=80)
#define NJOB  12500                     // 4 queries per job (wave)

// ---------------------------------------------------------------------------
// Pack kernel: s_pts -> one dword per point (3 x 10-bit quantized coords).
// ---------------------------------------------------------------------------
__global__ __launch_bounds__(256) void pack_kernel(const float* __restrict__ s_pts,
                                                   uint32_t* __restrict__ packed)
{
    int i = blockIdx.x * 256 + threadIdx.x;
    if (i >= N_S) return;
    float px = s_pts[i * 3 + 0];
    float py = s_pts[i * 3 + 1];
    float pz = s_pts[i * 3 + 2];
    uint32_t ux = (uint32_t)fminf(fmaxf(px * QSCALE, 0.f), 1023.f);
    uint32_t uy = (uint32_t)fminf(fmaxf(py * QSCALE, 0.f), 1023.f);
    uint32_t uz = (uint32_t)fminf(fmaxf(pz * QSCALE, 0.f), 1023.f);
    packed[i] = ux | (uy << 10) | (uz << 20);
}

// ---------------------------------------------------------------------------
// Per-hit contribution (lane = output channel; zero inner-loop shuffles).
// Same-wave LDS write->read ordering handled by compiler lgkmcnt.
// ---------------------------------------------------------------------------
__device__ __forceinline__ float hit_contrib(
    int sidx, float rxs, float rys, float rzs, float* lfw, int lane,
    const float* __restrict__ x, const float* __restrict__ W_pre,
    const float* __restrict__ b_pre, const float* __restrict__ kp_w,
    const float* __restrict__ kpts)
{
    const float e2 = KP_EXT * KP_EXT;

    // stage source feature row into this wave's LDS slot (coalesced 256 B)
    lfw[lane] = x[(long)sidx * CH + lane];

    // preactivation GEMV: t[o] = b[o] + sum_i x[i] * W_pre[i][o]
    float t = b_pre[lane];
    #pragma unroll
    for (int i = 0; i < CH; ++i)
        t = fmaf(lfw[i], W_pre[i * CH + lane], t);
    float f = (t >= 0.f) ? t : NEG_SLOPE * t;

    // republish f through the same slot (lockstep: all reads precede write)
    lfw[lane] = f;

    float acc = 0.f;
    #pragma unroll 1
    for (int l = 0; l < NKP; ++l) {
        float dx = rxs - kpts[l * 3 + 0];
        float dy = rys - kpts[l * 3 + 1];
        float dz = rzs - kpts[l * 3 + 2];
        float d2 = dx * dx + dy * dy + dz * dz;
        if (d2 < e2) {
            float w = 1.f - sqrtf(d2) / KP_EXT;      // > 0 here
            const float* Wl = kp_w + (unsigned)(l * CH * CH);
            float partial = 0.f;
            #pragma unroll
            for (int i = 0; i < CH; ++i)
                partial = fmaf(lfw[i], Wl[i * CH + lane], partial);
            acc = fmaf(w, partial, acc);
        }
    }
    return acc;
}

// ---------------------------------------------------------------------------
// Fused sparse KPConv, one wave per 4 queries (2 pipelined scan rounds).
// r13 evidence: wave lifetime ~3.3us vs ~0.6us modeled work, gather only
// ~6.5us of 65 -> hypothesis: per-wave serial latency dominates. Fix: double
// work per wave (both rounds' inds loads + gathers issued together), halve
// wave count. Hit path identical to r13.
// ---------------------------------------------------------------------------
template<bool PACKED>
__global__ __launch_bounds__(256) void kpconv_kernel(
    const float* __restrict__ q_pts,    // [N_Q,3]
    const float* __restrict__ s_pts,    // [N_S,3]
    const int*   __restrict__ inds,     // [N_Q,KNB] int32 OR int64 (sniffed)
    const float* __restrict__ x,        // [N_S,CH]
    const float* __restrict__ W_pre,    // [CH,CH]
    const float* __restrict__ b_pre,    // [CH]
    const float* __restrict__ kp_w,     // [NKP,CH,CH]
    const float* __restrict__ kpts,     // [NKP,3]
    const uint32_t* __restrict__ packed,// [N_S] quantized coords (if PACKED)
    float* __restrict__ out)            // [N_Q,CH]
{
    __shared__ float lf[4][CH];         // per-wave staging (x-row, then f)

    const int lane = threadIdx.x & 63;
    const int wid  = threadIdx.x >> 6;
    const int job  = blockIdx.x * 4 + wid;      // 4 queries per job

    // layout sniff: int64 (LE) => high dwords of elems 0..3 are all zero.
    const bool i64 = (inds[1] == 0) & (inds[3] == 0) & (inds[5] == 0) & (inds[7] == 0);
    const float e2 = KP_EXT * KP_EXT;

    // ---- both rounds' pair loads issued together ----
    const long fp0 = (long)job * 128 + lane;    // queries 4j, 4j+1
    const long fp1 = fp0 + 64;                  // queries 4j+2, 4j+3
    const int  v0  = i64 ? reinterpret_cast<const int2*>(inds)[fp0].x : inds[fp0];
    const int  v1  = i64 ? reinterpret_cast<const int2*>(inds)[fp1].x : inds[fp1];

    const int qa = job * 4 + (lane >> 5);       // round-0 query for this lane
    const int qb = qa + 2;                      // round-1 query for this lane
    const float qx0 = q_pts[qa * 3 + 0];
    const float qy0 = q_pts[qa * 3 + 1];
    const float qz0 = q_pts[qa * 3 + 2];
    const float qx1 = q_pts[qb * 3 + 0];
    const float qy1 = q_pts[qb * 3 + 1];
    const float qz1 = q_pts[qb * 3 + 2];

    const int m_ = N_S + 1;                     // python-style mod (shadow = N_S)
    int idx0 = v0 % m_; if (idx0 < 0) idx0 += m_;
    int idx1 = v1 % m_; if (idx1 < 0) idx1 += m_;

    // ---- both gathers in flight together (clamped addr, uniform flow) ----
    bool cand0 = (idx0 < N_S);
    bool cand1 = (idx1 < N_S);
    if (PACKED) {
        uint32_t pk0 = packed[min(idx0, N_S - 1)];
        uint32_t pk1 = packed[min(idx1, N_S - 1)];
        int ax = (int)(qx0 * QSCALE), ay = (int)(qy0 * QSCALE), az = (int)(qz0 * QSCALE);
        int bx = (int)(qx1 * QSCALE), by = (int)(qy1 * QSCALE), bz = (int)(qz1 * QSCALE);
        cand0 &= (abs((int)(pk0 & 1023u) - ax) <= QTH)
               & (abs((int)((pk0 >> 10) & 1023u) - ay) <= QTH)
               & (abs((int)(pk0 >> 20) - az) <= QTH);
        cand1 &= (abs((int)(pk1 & 1023u) - bx) <= QTH)
               & (abs((int)((pk1 >> 10) & 1023u) - by) <= QTH)
               & (abs((int)(pk1 >> 20) - bz) <= QTH);
    }

    // ---- exact tests for the ~0.4% survivors ----
    float rx0 = 0.f, ry0 = 0.f, rz0 = 0.f;
    float rx1 = 0.f, ry1 = 0.f, rz1 = 0.f;
    bool hit0 = false, hit1 = false;
    if (cand0) {
        rx0 = s_pts[idx0 * 3 + 0] - qx0;
        ry0 = s_pts[idx0 * 3 + 1] - qy0;
        rz0 = s_pts[idx0 * 3 + 2] - qz0;
        if (fabsf(rx0) <= BBOX && fabsf(ry0) <= BBOX && fabsf(rz0) <= BBOX) {
            #pragma unroll 1
            for (int l = 0; l < NKP; ++l) {
                float dx = rx0 - kpts[l * 3 + 0];
                float dy = ry0 - kpts[l * 3 + 1];
                float dz = rz0 - kpts[l * 3 + 2];
                if (dx * dx + dy * dy + dz * dz < e2) { hit0 = true; break; }
            }
        }
    }
    if (cand1) {
        rx1 = s_pts[idx1 * 3 + 0] - qx1;
        ry1 = s_pts[idx1 * 3 + 1] - qy1;
        rz1 = s_pts[idx1 * 3 + 2] - qz1;
        if (fabsf(rx1) <= BBOX && fabsf(ry1) <= BBOX && fabsf(rz1) <= BBOX) {
            #pragma unroll 1
            for (int l = 0; l < NKP; ++l) {
                float dx = rx1 - kpts[l * 3 + 0];
                float dy = ry1 - kpts[l * 3 + 1];
                float dz = rz1 - kpts[l * 3 + 2];
                if (dx * dx + dy * dy + dz * dz < e2) { hit1 = true; break; }
            }
        }
    }

    unsigned long long mask0 = __ballot(hit0);
    unsigned long long mask1 = __ballot(hit1);

    float acc0 = 0.f, acc1 = 0.f, acc2 = 0.f, acc3 = 0.f;

    while (mask0) {
        const int src = __ffsll((long long)mask0) - 1;
        mask0 &= mask0 - 1;
        const int   sidx = __shfl(idx0, src, 64);
        const float rxs  = __shfl(rx0, src, 64);
        const float rys  = __shfl(ry0, src, 64);
        const float rzs  = __shfl(rz0, src, 64);
        float c = hit_contrib(sidx, rxs, rys, rzs, lf[wid], lane,
                              x, W_pre, b_pre, kp_w, kpts);
        if (src < 32) acc0 += c; else acc1 += c;
    }
    while (mask1) {
        const int src = __ffsll((long long)mask1) - 1;
        mask1 &= mask1 - 1;
        const int   sidx = __shfl(idx1, src, 64);
        const float rxs  = __shfl(rx1, src, 64);
        const float rys  = __shfl(ry1, src, 64);
        const float rzs  = __shfl(rz1, src, 64);
        float c = hit_contrib(sidx, rxs, rys, rzs, lf[wid], lane,
                              x, W_pre, b_pre, kp_w, kpts);
        if (src < 32) acc2 += c; else acc3 += c;
    }

    // each wave owns exactly queries 4j..4j+3 -> plain coalesced stores
    out[((long)job * 4 + 0) * CH + lane] = acc0;
    out[((long)job * 4 + 1) * CH + lane] = acc1;
    out[((long)job * 4 + 2) * CH + lane] = acc2;
    out[((long)job * 4 + 3) * CH + lane] = acc3;
}

// ---------------------------------------------------------------------------
extern "C" void kernel_launch(void* const* d_in, const int* in_sizes, int n_in,
                              void* d_out, int out_size, void* d_ws, size_t ws_size,
                              hipStream_t stream)
{
    const float* q_pts = (const float*)d_in[0];
    const float* s_pts = (const float*)d_in[1];
    const int*   inds  = (const int*)  d_in[2];
    const float* x     = (const float*)d_in[3];
    const float* W_pre = (const float*)d_in[4];
    const float* b_pre = (const float*)d_in[5];
    const float* kp_w  = (const float*)d_in[6];
    const float* kpts  = (const float*)d_in[7];
    float* out = (float*)d_out;

    const bool use_packed = ws_size >= (size_t)N_S * sizeof(uint32_t);
    uint32_t* packed = (uint32_t*)d_ws;

    if (use_packed) {
        pack_kernel<<<(N_S + 255) / 256, 256, 0, stream>>>(s_pts, packed);
        kpconv_kernel<true><<<NJOB / 4, 256, 0, stream>>>(q_pts, s_pts, inds, x,
                                                          W_pre, b_pre, kp_w, kpts,
                                                          packed, out);
    } else {
        kpconv_kernel<false><<<NJOB / 4, 256, 0, stream>>>(q_pts, s_pts, inds, x,
                                                           W_pre, b_pre, kp_w, kpts,
                                                           nullptr, out);
    }
}